// Round 4
// baseline (75.828 us; speedup 1.0000x reference)
//
#include <hip/hip_runtime.h>
#include <math.h>

// GAT: B=32, N=1024, F=64, H=3, D=16
constexpr int Bc = 32, Nn = 1024, Fc = 64, Hc = 3, Dc = 16;
constexpr float ALPHAc = 0.2f;
constexpr float L2E    = 1.44269504088896340736f;

typedef __bf16 bf16x8 __attribute__((ext_vector_type(8)));
typedef float  f32x4  __attribute__((ext_vector_type(4)));

__device__ __forceinline__ unsigned enc_f32(float x) {
    unsigned b = __builtin_bit_cast(unsigned, x);
    return (b & 0x80000000u) ? ~b : (b | 0x80000000u);
}
__device__ __forceinline__ float dec_f32(unsigned e) {
    unsigned b = (e & 0x80000000u) ? (e ^ 0x80000000u) : ~e;
    return __builtin_bit_cast(float, b);
}

// ---------------------------------------------------------------------------
// K0: pack adj>0 bits (bit j&7 of byte i*128+j/8) + rowful[i] flags.
// Block = 256 bytes = exactly 2 rows.
// ---------------------------------------------------------------------------
__global__ __launch_bounds__(256) void gat_pack(
    const float* __restrict__ adj, unsigned char* __restrict__ bits,
    int* __restrict__ rowful)
{
    __shared__ int rf[2];
    int t = threadIdx.x;
    if (t < 2) rf[t] = 1;
    __syncthreads();

    int idx = blockIdx.x * 256 + t;
    const float4* p = (const float4*)(adj + (size_t)idx * 8);
    float4 x = p[0], y = p[1];
    unsigned b = 0;
    b |= (x.x > 0.f) ? 1u   : 0u;
    b |= (x.y > 0.f) ? 2u   : 0u;
    b |= (x.z > 0.f) ? 4u   : 0u;
    b |= (x.w > 0.f) ? 8u   : 0u;
    b |= (y.x > 0.f) ? 16u  : 0u;
    b |= (y.y > 0.f) ? 32u  : 0u;
    b |= (y.z > 0.f) ? 64u  : 0u;
    b |= (y.w > 0.f) ? 128u : 0u;
    bits[idx] = (unsigned char)b;
    if (b != 0xffu) atomicAnd(&rf[t >> 7], 0);
    __syncthreads();
    if (t == 0)   rowful[blockIdx.x * 2]     = rf[0];
    if (t == 128) rowful[blockIdx.x * 2 + 1] = rf[1];
}

// ---------------------------------------------------------------------------
// K1: Wh = h @ W per (b,h,n). Store Wh fp32 [bh][n][d] (fast path),
// WhT bf16 [bh][d][n] (fallback), s1/s2 fp32.
// ---------------------------------------------------------------------------
__global__ __launch_bounds__(256) void gat_stage1(
    const float* __restrict__ hbuf, const float* __restrict__ W,
    const float* __restrict__ a, float* __restrict__ Whf,
    __bf16* __restrict__ WhT, float* __restrict__ s1, float* __restrict__ s2)
{
    int idx = blockIdx.x * 256 + threadIdx.x;       // (b*H + h)*N + n
    int n  = idx & (Nn - 1);
    int bh = idx >> 10;
    int hh = bh % Hc;
    int b  = bh / Hc;

    const float4* hrow = (const float4*)(hbuf + ((size_t)b * Nn + n) * Fc);
    const float*  Wp   = W + (size_t)hh * Fc * Dc;

    float acc[Dc];
#pragma unroll
    for (int d = 0; d < Dc; ++d) acc[d] = 0.f;

#pragma unroll
    for (int q16 = 0; q16 < Fc / 4; ++q16) {
        float4 hv4 = hrow[q16];
#pragma unroll
        for (int c = 0; c < 4; ++c) {
            float hv = (c == 0) ? hv4.x : (c == 1) ? hv4.y : (c == 2) ? hv4.z : hv4.w;
            int f = 4 * q16 + c;
            const float4* wr = (const float4*)(Wp + f * Dc);
#pragma unroll
            for (int q = 0; q < 4; ++q) {
                float4 wv = wr[q];
                acc[4*q+0] = fmaf(hv, wv.x, acc[4*q+0]);
                acc[4*q+1] = fmaf(hv, wv.y, acc[4*q+1]);
                acc[4*q+2] = fmaf(hv, wv.z, acc[4*q+2]);
                acc[4*q+3] = fmaf(hv, wv.w, acc[4*q+3]);
            }
        }
    }

    float4* wf = (float4*)(Whf + (size_t)idx * Dc);
#pragma unroll
    for (int q = 0; q < 4; ++q)
        wf[q] = make_float4(acc[4*q+0], acc[4*q+1], acc[4*q+2], acc[4*q+3]);
#pragma unroll
    for (int d = 0; d < Dc; ++d)
        WhT[((size_t)bh * Dc + d) * Nn + n] = (__bf16)acc[d];

    const float* ap = a + (size_t)hh * 2 * Dc;
    float t1 = 0.f, t2 = 0.f;
#pragma unroll
    for (int d = 0; d < Dc; ++d) {
        t1 = fmaf(acc[d], ap[d],      t1);
        t2 = fmaf(acc[d], ap[Dc + d], t2);
    }
    s1[idx] = t1;
    s2[idx] = t2;
}

// ---------------------------------------------------------------------------
// K2: per bh — bitonic sort j by s2; exclusive prefix sums over sorted order
// of v_j = (B*Wh[0..15], D*Wh[0..15], B, D), B=2^(s2*L2E), D=2^(0.2*s2*L2E).
// PS[bh][p][36] p=0..1024 (1024 = totals); ss2[bh][p] = sorted s2.
// One block (256 thr) per bh.
// ---------------------------------------------------------------------------
__global__ __launch_bounds__(256) void gat_sortscan(
    const float* __restrict__ s2g, const float* __restrict__ Whf,
    float* __restrict__ PS, float* __restrict__ ss2)
{
    __shared__ unsigned long long keys[Nn];
    __shared__ float wtot[4][34];

    int bh = blockIdx.x, t = threadIdx.x;

    {
        float4 v = ((const float4*)(s2g + (size_t)bh * Nn))[t];
        float sv[4] = {v.x, v.y, v.z, v.w};
#pragma unroll
        for (int q = 0; q < 4; ++q)
            keys[4*t+q] = ((unsigned long long)enc_f32(sv[q]) << 32) | (unsigned)(4*t+q);
    }

    // bitonic sort ascending (encoded s2 in upper 32 bits)
    for (int k = 2; k <= Nn; k <<= 1) {
        for (int s = k >> 1; s > 0; s >>= 1) {
            __syncthreads();
#pragma unroll
            for (int w = 0; w < 2; ++w) {
                int t2 = t + 256 * w;
                int i1 = ((t2 & ~(s - 1)) << 1) | (t2 & (s - 1));
                int i2 = i1 | s;
                unsigned long long ka = keys[i1], kb = keys[i2];
                bool up = ((i1 & k) == 0);
                if ((ka > kb) == up) { keys[i1] = kb; keys[i2] = ka; }
            }
        }
    }
    __syncthreads();

    const float* Wb = Whf + (size_t)bh * Nn * Dc;

    // pass A: local totals over p = 4t..4t+3
    float T[34];
#pragma unroll
    for (int c = 0; c < 34; ++c) T[c] = 0.f;
    for (int q = 0; q < 4; ++q) {
        unsigned long long kk = keys[4*t+q];
        int   j   = (int)(kk & 0xffffffffull);
        float s2v = dec_f32((unsigned)(kk >> 32));
        float Bv  = __builtin_amdgcn_exp2f(s2v * L2E);
        float Dv  = __builtin_amdgcn_exp2f(s2v * (ALPHAc * L2E));
        const float4* wr = (const float4*)(Wb + (size_t)j * Dc);
        float4 w0 = wr[0], w1 = wr[1], w2 = wr[2], w3 = wr[3];
        float wh[16] = {w0.x,w0.y,w0.z,w0.w, w1.x,w1.y,w1.z,w1.w,
                        w2.x,w2.y,w2.z,w2.w, w3.x,w3.y,w3.z,w3.w};
#pragma unroll
        for (int d = 0; d < 16; ++d) {
            T[d]      = fmaf(Bv, wh[d], T[d]);
            T[16 + d] = fmaf(Dv, wh[d], T[16 + d]);
        }
        T[32] += Bv; T[33] += Dv;
    }

    // exclusive scan across 256 threads (wave shuffles + LDS wave offsets)
    int lane = t & 63, wv = t >> 6;
    float base[34];
#pragma unroll
    for (int c = 0; c < 34; ++c) {
        float x = T[c];
#pragma unroll
        for (int off = 1; off < 64; off <<= 1) {
            float o = __shfl_up(x, off, 64);
            if (lane >= off) x += o;
        }
        if (lane == 63) wtot[wv][c] = x;
        base[c] = x - T[c];
    }
    __syncthreads();
#pragma unroll
    for (int c = 0; c < 34; ++c) {
        for (int w = 0; w < 3; ++w)
            if (w < wv) base[c] += wtot[w][c];
    }

    // pass B: write exclusive prefixes + sorted s2, walk base forward
    float* PSb = PS + (size_t)bh * 1025 * 36;
    for (int q = 0; q < 4; ++q) {
        int p = 4*t + q;
        unsigned long long kk = keys[p];
        int   j   = (int)(kk & 0xffffffffull);
        float s2v = dec_f32((unsigned)(kk >> 32));
        float Bv  = __builtin_amdgcn_exp2f(s2v * L2E);
        float Dv  = __builtin_amdgcn_exp2f(s2v * (ALPHAc * L2E));
        ss2[(size_t)bh * Nn + p] = s2v;
        float* row = PSb + (size_t)p * 36;
#pragma unroll
        for (int c = 0; c < 34; ++c) row[c] = base[c];
        const float4* wr = (const float4*)(Wb + (size_t)j * Dc);
        float4 w0 = wr[0], w1 = wr[1], w2 = wr[2], w3 = wr[3];
        float wh[16] = {w0.x,w0.y,w0.z,w0.w, w1.x,w1.y,w1.z,w1.w,
                        w2.x,w2.y,w2.z,w2.w, w3.x,w3.y,w3.z,w3.w};
#pragma unroll
        for (int d = 0; d < 16; ++d) {
            base[d]      = fmaf(Bv, wh[d], base[d]);
            base[16 + d] = fmaf(Dv, wh[d], base[16 + d]);
        }
        base[32] += Bv; base[33] += Dv;
    }
    if (t == 255) {
        float* row = PSb + (size_t)1024 * 36;   // grand totals
#pragma unroll
        for (int c = 0; c < 34; ++c) row[c] = base[c];
    }
}

// ---------------------------------------------------------------------------
// K3: per (bh,i) with rowful[i]: binary-search split p, combine prefixes.
//   out_i = [(TB - PB[p]) + R_i*PD[p]] / [(TBz - PBz[p]) + R_i*PDz[p]]
// Block = 256 threads = 256 i's of one bh quarter; grid = 96*4.
// ---------------------------------------------------------------------------
__global__ __launch_bounds__(256) void gat_combine(
    const float* __restrict__ PS, const float* __restrict__ ss2,
    const float* __restrict__ s1g, const int* __restrict__ rowful,
    float* __restrict__ out)
{
    __shared__ __align__(16) float s2s[Nn];
    __shared__ __align__(16) float TS[36];

    int blk = blockIdx.x;
    int bh = blk >> 2, quarter = blk & 3;
    int hh = bh % Hc, b = bh / Hc;
    int t = threadIdx.x;

    ((float4*)s2s)[t] = ((const float4*)(ss2 + (size_t)bh * Nn))[t];
    if (t < 34) TS[t] = PS[((size_t)bh * 1025 + 1024) * 36 + t];
    __syncthreads();

    int i = quarter * 256 + t;
    if (!rowful[i]) return;          // fallback kernel owns this row

    float s1v = s1g[(size_t)bh * Nn + i];
    float th  = -s1v;
    float R   = __builtin_amdgcn_exp2f(-0.8f * L2E * s1v);

    int p = 0;
#pragma unroll
    for (int step = 512; step >= 1; step >>= 1)
        if (s2s[p + step - 1] <= th) p += step;
    if (s2s[p] <= th) ++p;           // p in [0,1024]

    const f32x4* Pp = (const f32x4*)(PS + ((size_t)bh * 1025 + p) * 36);
    const f32x4* Tp = (const f32x4*)TS;
    f32x4 A8 = Pp[8];                // [B, D, pad, pad]
    float den = (TS[32] - A8[0]) + R * A8[1];
    float inv = 1.0f / den;

    float* op = out + ((size_t)b * Nn + i) * (Hc * Dc) + hh * Dc;
#pragma unroll
    for (int q = 0; q < 4; ++q) {
        f32x4 nq = (Tp[q] - Pp[q]) + R * Pp[4 + q];
        *(f32x4*)(op + 4 * q) = nq * inv;
    }
}

// ---------------------------------------------------------------------------
// K4: fallback for rows with masked entries (general adj). With full rows the
// whole block early-exits. Same MFMA flash loop as R3, c2=0, max-trick.
// ---------------------------------------------------------------------------
__global__ __launch_bounds__(256) void gat_attn_mfma(
    const __bf16* __restrict__ WhT, const float* __restrict__ s1g,
    const float* __restrict__ s2g, const unsigned char* __restrict__ adjbits,
    const int* __restrict__ rowful, float* __restrict__ out)
{
    __shared__ __align__(16) unsigned s2pk[Nn];
    __shared__ int allok;

    int bid  = blockIdx.x;
    int tile = bid & 15;
    int bh   = bid >> 4;
    int hh   = bh % Hc;
    int b    = bh / Hc;
    int t    = threadIdx.x;
    int i0   = tile * 64;

    if (t == 0) allok = 1;
    __syncthreads();
    if (t < 64 && !rowful[i0 + t]) atomicAnd(&allok, 0);
    __syncthreads();
    if (allok) return;               // fast path covered every row

    {
        float4 v = ((const float4*)(s2g + (size_t)bh * Nn))[t];
        unsigned pk[4];
        float sv[4] = {v.x, v.y, v.z, v.w};
#pragma unroll
        for (int q = 0; q < 4; ++q) {
            float Bf = __builtin_amdgcn_exp2f(sv[q] * L2E);
            float Df = __builtin_amdgcn_exp2f(sv[q] * (ALPHAc * L2E));
            unsigned bb = (unsigned)__builtin_bit_cast(unsigned short, (__bf16)Bf);
            unsigned db = (unsigned)__builtin_bit_cast(unsigned short, (__bf16)Df);
            pk[q] = (db << 16) | bb;
        }
        ((uint4*)s2pk)[t] = make_uint4(pk[0], pk[1], pk[2], pk[3]);
    }
    __syncthreads();

    int wave = t >> 6;
    int l    = t & 63;
    int lr   = l & 15;
    int lg   = l >> 4;

    int i = i0 + wave * 16 + lr;
    float s1v = s1g[(size_t)bh * Nn + i];
    float R   = __builtin_amdgcn_exp2f(s1v * (-0.8f * L2E));

    const __bf16* Ap   = WhT + ((size_t)bh * Dc + lr) * Nn + lg * 8;
    const uint4*  abp4 = (const uint4*)(adjbits + (size_t)i * (Nn / 8));

    bf16x8 ones;
#pragma unroll
    for (int e = 0; e < 8; ++e) ones[e] = (__bf16)1.0f;

    f32x4 acc  = {0.f, 0.f, 0.f, 0.f};
    f32x4 accz = {0.f, 0.f, 0.f, 0.f};

    uint4 mnext = abp4[0];
    for (int o = 0; o < 8; ++o) {
        uint4 mrow = mnext;
        if (o < 7) mnext = abp4[o + 1];
#pragma unroll
        for (int q = 0; q < 4; ++q) {
            unsigned w32 = (q == 0) ? mrow.x : (q == 1) ? mrow.y
                         : (q == 2) ? mrow.z : mrow.w;
            int j0 = o * 128 + q * 32;
            unsigned m8 = (w32 >> (lg * 8)) & 0xffu;

            const uint4* sp = (const uint4*)&s2pk[j0 + lg * 8];
            uint4 pa = sp[0], pb = sp[1];
            unsigned pk8[8] = {pa.x, pa.y, pa.z, pa.w, pb.x, pb.y, pb.z, pb.w};

            bf16x8 pfrag;
#pragma unroll
            for (int e = 0; e < 8; ++e) {
                unsigned u = pk8[e];
                float Bf = __builtin_bit_cast(float, u << 16);
                float Df = __builtin_bit_cast(float, u & 0xffff0000u);
                float w  = fmaxf(Bf, R * Df);
                pfrag[e] = (__bf16)w;
            }
            if (!__all((int)(m8 == 0xffu))) {
#pragma unroll
                for (int e = 0; e < 8; ++e)
                    if (!(m8 & (1u << e))) pfrag[e] = (__bf16)0.f;
            }

            bf16x8 afrag = *(const bf16x8*)(Ap + j0);
            acc  = __builtin_amdgcn_mfma_f32_16x16x32_bf16(afrag, pfrag, acc,  0, 0, 0);
            accz = __builtin_amdgcn_mfma_f32_16x16x32_bf16(ones,  pfrag, accz, 0, 0, 0);
        }
    }

    if (!rowful[i]) {
        float inv = 1.0f / accz[0];
        float* op = out + ((size_t)b * Nn + i) * (Hc * Dc) + hh * Dc + lg * 4;
        *(float4*)op = make_float4(acc[0] * inv, acc[1] * inv, acc[2] * inv, acc[3] * inv);
    }
}

// ---------------------------------------------------------------------------
extern "C" void kernel_launch(void* const* d_in, const int* in_sizes, int n_in,
                              void* d_out, int out_size, void* d_ws, size_t ws_size,
                              hipStream_t stream)
{
    const float* hbuf = (const float*)d_in[0];   // (B,N,F)
    const float* adj  = (const float*)d_in[1];   // (N,N)
    const float* W    = (const float*)d_in[2];   // (H,F,D)
    const float* a    = (const float*)d_in[3];   // (H,2D,1)
    float* out = (float*)d_out;                  // (B,N,H*D) fp32

    // ws layout (~25 MB): Whf f32 | PS f32 | s1 | s2 | ss2 | WhT bf16 | adjbits | rowful
    float* Whf = (float*)d_ws;                                   // 96*1024*16
    float* PS  = Whf + (size_t)Bc * Hc * Nn * Dc;                // 96*1025*36
    float* s1  = PS + (size_t)Bc * Hc * 1025 * 36;
    float* s2  = s1 + (size_t)Bc * Hc * Nn;
    float* ss2 = s2 + (size_t)Bc * Hc * Nn;
    __bf16* WhT = (__bf16*)(ss2 + (size_t)Bc * Hc * Nn);         // 96*16*1024
    unsigned char* adjbits = (unsigned char*)(WhT + (size_t)Bc * Hc * Dc * Nn);
    int* rowful = (int*)(adjbits + (size_t)Nn * Nn / 8);

    gat_pack<<<dim3(Nn * Nn / 8 / 256), dim3(256), 0, stream>>>(adj, adjbits, rowful);
    gat_stage1<<<dim3((Bc * Hc * Nn) / 256), dim3(256), 0, stream>>>(
        hbuf, W, a, Whf, WhT, s1, s2);
    gat_sortscan<<<dim3(Bc * Hc), dim3(256), 0, stream>>>(s2, Whf, PS, ss2);
    gat_combine<<<dim3(Bc * Hc * 4), dim3(256), 0, stream>>>(PS, ss2, s1, rowful, out);
    gat_attn_mfma<<<dim3(Bc * Hc * 16), dim3(256), 0, stream>>>(
        WhT, s1, s2, adjbits, rowful, out);
}

// Round 5
// 60.212 us; speedup vs baseline: 1.2593x; 1.2593x over previous
//
#include <hip/hip_runtime.h>
#include <math.h>

// GAT: B=32, N=1024, F=64, H=3, D=16
constexpr int Bc = 32, Nn = 1024, Fc = 64, Hc = 3, Dc = 16;
constexpr float ALPHAc = 0.2f;
constexpr float L2E    = 1.44269504088896340736f;

__device__ __forceinline__ unsigned enc_f32(float x) {
    unsigned b = __builtin_bit_cast(unsigned, x);
    return (b & 0x80000000u) ? ~b : (b | 0x80000000u);
}

// ---------------------------------------------------------------------------
// K0: rowful[i] = all(adj[i][:] > 0).  One block per row.
// ---------------------------------------------------------------------------
__global__ __launch_bounds__(256) void gat_rowful(
    const float* __restrict__ adj, int* __restrict__ rowful)
{
    __shared__ int rf;
    int row = blockIdx.x, t = threadIdx.x;
    if (t == 0) rf = 1;
    __syncthreads();
    float4 v = ((const float4*)(adj + (size_t)row * Nn))[t];
    bool ok = (v.x > 0.f) && (v.y > 0.f) && (v.z > 0.f) && (v.w > 0.f);
    if (!__all((int)ok)) {
        if ((t & 63) == 0) atomicAnd(&rf, 0);
    }
    __syncthreads();
    if (t == 0) rowful[row] = rf;
}

// ---------------------------------------------------------------------------
// K1: one block per (b,h), 1024 threads. Everything in LDS:
//  P0: thread t=n computes Wh row (64x16 FMA), s1, s2; Whf->global (L2).
//  P1: rank-sort by s2 (u64 keys; each thread counts keys < its own).
//  P2: per sorted slot: v[34] = (B*Wh, D*Wh, B, D); exclusive block scan
//      -> PS[1025][35] in LDS (PS row 1024 = grand totals).
//  P3: thread t = row i: binary search split p, O(1) combine:
//      out_i = [(TB-PB[p]) + R_i*PD[p]] / [(TBz-PBz[p]) + R_i*PDz[p]]
//  Masked rows (rowful=0): exact per-thread fallback loop over adj row.
// ---------------------------------------------------------------------------
__global__ __launch_bounds__(1024, 1) void gat_fused(
    const float* __restrict__ hbuf, const float* __restrict__ W,
    const float* __restrict__ a, const float* __restrict__ adj,
    const int* __restrict__ rowful, float* Whf, float* __restrict__ out)
{
    // 143,500 + 4,096*3 + 2,176 = 157,964 B LDS
    __shared__ __align__(16) float PS[1025 * 35];  // prefix table; aliased as keys during rank
    __shared__ __align__(16) float s2s[Nn];        // sorted s2
    __shared__ __align__(16) int   js[Nn];         // sorted -> original index
    __shared__ __align__(16) float s2o[Nn];        // s2 by original index (slow path)
    __shared__ float wtot[16][34];

    int bh = blockIdx.x;
    int hh = bh % Hc, b = bh / Hc;
    int t  = threadIdx.x;            // = n in P0; sorted slot in P2; row i in P3
    int wv = t >> 6, lane = t & 63;

    // ---------------- P0: Wh, s1, s2 ----------------
    const float4* h4 = (const float4*)(hbuf + ((size_t)b * Nn + t) * Fc);
    const float*  Wp = W + (size_t)hh * Fc * Dc;

    float acc[Dc];
#pragma unroll
    for (int d = 0; d < Dc; ++d) acc[d] = 0.f;

#pragma unroll
    for (int q = 0; q < Fc / 4; ++q) {
        float4 hv = h4[q];
#pragma unroll
        for (int c = 0; c < 4; ++c) {
            float hv1 = (c == 0) ? hv.x : (c == 1) ? hv.y : (c == 2) ? hv.z : hv.w;
            const float4* wrp = (const float4*)(Wp + (4 * q + c) * Dc);
#pragma unroll
            for (int u = 0; u < 4; ++u) {
                float4 wq = wrp[u];
                acc[4*u+0] = fmaf(hv1, wq.x, acc[4*u+0]);
                acc[4*u+1] = fmaf(hv1, wq.y, acc[4*u+1]);
                acc[4*u+2] = fmaf(hv1, wq.z, acc[4*u+2]);
                acc[4*u+3] = fmaf(hv1, wq.w, acc[4*u+3]);
            }
        }
    }

    float4* wf = (float4*)(Whf + ((size_t)bh * Nn + t) * Dc);
#pragma unroll
    for (int u = 0; u < 4; ++u)
        wf[u] = make_float4(acc[4*u+0], acc[4*u+1], acc[4*u+2], acc[4*u+3]);

    const float* ap = a + (size_t)hh * 2 * Dc;
    float s1v = 0.f, s2v = 0.f;
#pragma unroll
    for (int d = 0; d < Dc; ++d) {
        s1v = fmaf(acc[d], ap[d],      s1v);
        s2v = fmaf(acc[d], ap[Dc + d], s2v);
    }
    s2o[t] = s2v;

    unsigned long long* keys = (unsigned long long*)PS;   // alias (dead before PS writes)
    keys[t] = ((unsigned long long)enc_f32(s2v) << 32) | (unsigned)t;
    __syncthreads();

    // ---------------- P1: rank sort ----------------
    unsigned long long kt = keys[t];
    int r = 0;
    const ulonglong2* kp = (const ulonglong2*)keys;
#pragma unroll 8
    for (int q = 0; q < Nn / 2; ++q) {
        ulonglong2 kk = kp[q];          // broadcast read (uniform addr)
        r += (kk.x < kt) ? 1 : 0;
        r += (kk.y < kt) ? 1 : 0;
    }
    s2s[r] = s2v;
    js[r]  = t;
    __syncthreads();

    // ---------------- P2: v + block exclusive scan -> PS ----------------
    int   j  = js[t];
    float sv = s2s[t];
    float Bv = __builtin_amdgcn_exp2f(sv * L2E);
    float Dv = __builtin_amdgcn_exp2f(sv * (ALPHAc * L2E));
    const float4* wr = (const float4*)(Whf + ((size_t)bh * Nn + j) * Dc);
    float4 w0 = wr[0], w1 = wr[1], w2 = wr[2], w3 = wr[3];
    float wh[16] = {w0.x,w0.y,w0.z,w0.w, w1.x,w1.y,w1.z,w1.w,
                    w2.x,w2.y,w2.z,w2.w, w3.x,w3.y,w3.z,w3.w};

    float v[34];
#pragma unroll
    for (int d = 0; d < 16; ++d) {
        v[d]      = Bv * wh[d];
        v[16 + d] = Dv * wh[d];
    }
    v[32] = Bv; v[33] = Dv;

    // wave-level exclusive scan per channel; lane63 stores wave total
#pragma unroll
    for (int c = 0; c < 34; ++c) {
        float x = v[c];
#pragma unroll
        for (int off = 1; off < 64; off <<= 1) {
            float o = __shfl_up(x, off, 64);
            if (lane >= off) x += o;
        }
        if (lane == 63) wtot[wv][c] = x;       // inclusive wave total
        float e = __shfl_up(x, 1, 64);
        v[c] = (lane == 0) ? 0.f : e;          // exclusive within wave
    }
    __syncthreads();

    // serial scan of the 16 wave totals per channel (threads 0..33)
    if (t < 34) {
        float run = 0.f;
#pragma unroll
        for (int w = 0; w < 16; ++w) {
            float tmp = wtot[w][t];
            wtot[w][t] = run;                  // exclusive wave offset
            run += tmp;
        }
        PS[(size_t)1024 * 35 + t] = run;       // grand totals
    }
    __syncthreads();

    float* myrow = PS + (size_t)t * 35;        // stride 35 -> conflict-free
#pragma unroll
    for (int c = 0; c < 34; ++c)
        myrow[c] = v[c] + wtot[wv][c];
    __syncthreads();

    // ---------------- P3: combine ----------------
    int i = t;
    float th = -s1v;
    float R  = __builtin_amdgcn_exp2f(-0.8f * L2E * s1v);
    float* op = out + ((size_t)b * Nn + i) * (Hc * Dc) + hh * Dc;

    if (rowful[i]) {
        int p = 0;
#pragma unroll
        for (int step = 512; step >= 1; step >>= 1)
            if (s2s[p + step - 1] <= th) p += step;
        if (s2s[p] <= th) ++p;                 // p in [0,1024]

        const float* Pp = PS + (size_t)p * 35;
        const float* Tp = PS + (size_t)1024 * 35;
        float den = (Tp[32] - Pp[32]) + R * Pp[33];
        float inv = 1.0f / den;
#pragma unroll
        for (int u = 0; u < 4; ++u) {
            float o0 = ((Tp[4*u+0] - Pp[4*u+0]) + R * Pp[16 + 4*u+0]) * inv;
            float o1 = ((Tp[4*u+1] - Pp[4*u+1]) + R * Pp[16 + 4*u+1]) * inv;
            float o2 = ((Tp[4*u+2] - Pp[4*u+2]) + R * Pp[16 + 4*u+2]) * inv;
            float o3 = ((Tp[4*u+3] - Pp[4*u+3]) + R * Pp[16 + 4*u+3]) * inv;
            ((float4*)op)[u] = make_float4(o0, o1, o2, o3);
        }
    } else {
        // exact fallback for masked rows (unused when adj is all-positive)
        float num[16];
#pragma unroll
        for (int d = 0; d < 16; ++d) num[d] = 0.f;
        float den = 0.f;
        for (int q = 0; q < Nn; ++q) {
            float aq = adj[(size_t)i * Nn + q];
            if (aq > 0.f) {
                float sq = s2o[q];
                float Bq = __builtin_amdgcn_exp2f(sq * L2E);
                float Dq = __builtin_amdgcn_exp2f(sq * (ALPHAc * L2E));
                float w_ = fmaxf(Bq, R * Dq);
                den += w_;
                const float* wq = Whf + ((size_t)bh * Nn + q) * Dc;
#pragma unroll
                for (int d = 0; d < 16; ++d)
                    num[d] = fmaf(w_, wq[d], num[d]);
            }
        }
        float inv = 1.0f / den;
#pragma unroll
        for (int d = 0; d < 16; ++d) op[d] = num[d] * inv;
    }
}

// ---------------------------------------------------------------------------
extern "C" void kernel_launch(void* const* d_in, const int* in_sizes, int n_in,
                              void* d_out, int out_size, void* d_ws, size_t ws_size,
                              hipStream_t stream)
{
    const float* hbuf = (const float*)d_in[0];   // (B,N,F)
    const float* adj  = (const float*)d_in[1];   // (N,N)
    const float* W    = (const float*)d_in[2];   // (H,F,D)
    const float* a    = (const float*)d_in[3];   // (H,2D,1)
    float* out = (float*)d_out;                  // (B,N,H*D) fp32

    // ws: Whf f32 (96*1024*16 = 6.3 MB) | rowful (1024 ints)
    float* Whf  = (float*)d_ws;
    int* rowful = (int*)(Whf + (size_t)Bc * Hc * Nn * Dc);

    gat_rowful<<<dim3(Nn), dim3(256), 0, stream>>>(adj, rowful);
    gat_fused<<<dim3(Bc * Hc), dim3(1024), 0, stream>>>(
        hbuf, W, a, adj, rowful, Whf, out);
}

// Round 6
// 44.284 us; speedup vs baseline: 1.7123x; 1.3597x over previous
//
#include <hip/hip_runtime.h>
#include <math.h>

// GAT: B=32, N=1024, F=64, H=3, D=16
constexpr int Bc = 32, Nn = 1024, Fc = 64, Hc = 3, Dc = 16;
constexpr float ALPHAc = 0.2f;
constexpr float L2E    = 1.44269504088896340736f;

__device__ __forceinline__ unsigned enc_f32(float x) {
    unsigned b = __builtin_bit_cast(unsigned, x);
    return (b & 0x80000000u) ? ~b : (b | 0x80000000u);
}

// ---------------------------------------------------------------------------
// K0: rowful[i] = all(adj[i][:] > 0).  One block per row.
// ---------------------------------------------------------------------------
__global__ __launch_bounds__(256) void gat_rowful(
    const float* __restrict__ adj, int* __restrict__ rowful)
{
    __shared__ int rf;
    int row = blockIdx.x, t = threadIdx.x;
    if (t == 0) rf = 1;
    __syncthreads();
    float4 v = ((const float4*)(adj + (size_t)row * Nn))[t];
    bool ok = (v.x > 0.f) && (v.y > 0.f) && (v.z > 0.f) && (v.w > 0.f);
    if (!__all((int)ok)) {
        if ((t & 63) == 0) atomicAnd(&rf, 0);
    }
    __syncthreads();
    if (t == 0) rowful[row] = rf;
}

// ---------------------------------------------------------------------------
// K1: one block per (b,h), 1024 threads.
//  P0: thread t=n: Wh row (64x16 FMA), s1, s2; Whf->global(L2); s2o->LDS.
//  P1: hybrid bitonic sort of u32 keys (22b truncated s2 | 10b index):
//      wave-local stages in registers (shfl), only s>=64 stages via LDS.
//  P2: sorted slot t: v[34]=(B*Wh, D*Wh, B, D); block exclusive scan ->
//      PS[1025][35] in LDS (row 1024 = grand totals).
//  P3: row i=t: binary search split p on keys, O(1) combine:
//      out_i = [(TB-PB[p]) + R_i*PD[p]] / [(TBz-PBz[p]) + R_i*PDz[p]]
//  Masked rows (rowful=0): exact per-thread fallback over adj row.
// ---------------------------------------------------------------------------
__global__ __launch_bounds__(1024, 1) void gat_fused(
    const float* __restrict__ hbuf, const float* __restrict__ W,
    const float* __restrict__ a, const float* __restrict__ adj,
    const int* __restrict__ rowful, float* Whf, float* __restrict__ out)
{
    // 143,500 + 4,096 + 4,096 + 2,176 = 153,868 B LDS
    __shared__ __align__(16) float    PS[1025 * 35];
    __shared__ __align__(16) unsigned skeys[Nn];
    __shared__ __align__(16) float    s2o[Nn];
    __shared__ float wtot[16][34];

    int bh = blockIdx.x;
    int hh = bh % Hc, b = bh / Hc;
    int t  = threadIdx.x;            // n in P0; sorted slot in P2; row i in P3
    int wv = t >> 6, lane = t & 63;

    // ---------------- P0: Wh, s1, s2 ----------------
    const float4* h4 = (const float4*)(hbuf + ((size_t)b * Nn + t) * Fc);
    const float*  Wp = W + (size_t)hh * Fc * Dc;

    float acc[Dc];
#pragma unroll
    for (int d = 0; d < Dc; ++d) acc[d] = 0.f;

#pragma unroll
    for (int q = 0; q < Fc / 4; ++q) {
        float4 hv = h4[q];
#pragma unroll
        for (int c = 0; c < 4; ++c) {
            float hv1 = (c == 0) ? hv.x : (c == 1) ? hv.y : (c == 2) ? hv.z : hv.w;
            const float4* wrp = (const float4*)(Wp + (4 * q + c) * Dc);
#pragma unroll
            for (int u = 0; u < 4; ++u) {
                float4 wq = wrp[u];
                acc[4*u+0] = fmaf(hv1, wq.x, acc[4*u+0]);
                acc[4*u+1] = fmaf(hv1, wq.y, acc[4*u+1]);
                acc[4*u+2] = fmaf(hv1, wq.z, acc[4*u+2]);
                acc[4*u+3] = fmaf(hv1, wq.w, acc[4*u+3]);
            }
        }
    }

    float4* wf = (float4*)(Whf + ((size_t)bh * Nn + t) * Dc);
#pragma unroll
    for (int u = 0; u < 4; ++u)
        wf[u] = make_float4(acc[4*u+0], acc[4*u+1], acc[4*u+2], acc[4*u+3]);

    const float* ap = a + (size_t)hh * 2 * Dc;
    float s1v = 0.f, s2v = 0.f;
#pragma unroll
    for (int d = 0; d < Dc; ++d) {
        s1v = fmaf(acc[d], ap[d],      s1v);
        s2v = fmaf(acc[d], ap[Dc + d], s2v);
    }
    s2o[t] = s2v;

    // ---------------- P1: hybrid bitonic sort (u32 keys) ----------------
    unsigned key = (enc_f32(s2v) & ~1023u) | (unsigned)t;

    // wave-local stages (k=2..64) — registers only
#pragma unroll
    for (int k = 2; k <= 64; k <<= 1) {
#pragma unroll
        for (int s = k >> 1; s >= 1; s >>= 1) {
            unsigned other = (unsigned)__shfl_xor((int)key, s, 64);
            bool dirUp = ((t & k) == 0);
            bool lower = ((lane & s) == 0);
            unsigned mn = key < other ? key : other;
            unsigned mx = key < other ? other : key;
            key = (lower == dirUp) ? mn : mx;
        }
    }
    // cross-wave merges (k=128..1024): s>=64 via LDS, tails in registers
#pragma unroll
    for (int k = 128; k <= 1024; k <<= 1) {
#pragma unroll
        for (int s = k >> 1; s >= 64; s >>= 1) {
            __syncthreads();
            skeys[t] = key;
            __syncthreads();
            unsigned other = skeys[t ^ s];
            bool dirUp = ((t & k) == 0);
            bool lower = ((t & s) == 0);
            unsigned mn = key < other ? key : other;
            unsigned mx = key < other ? other : key;
            key = (lower == dirUp) ? mn : mx;
        }
#pragma unroll
        for (int s = 32; s >= 1; s >>= 1) {
            unsigned other = (unsigned)__shfl_xor((int)key, s, 64);
            bool dirUp = ((t & k) == 0);
            bool lower = ((lane & s) == 0);
            unsigned mn = key < other ? key : other;
            unsigned mx = key < other ? other : key;
            key = (lower == dirUp) ? mn : mx;
        }
    }
    __syncthreads();
    skeys[t] = key;                  // sorted ascending (visible after P2 barriers)

    // ---------------- P2: v + block exclusive scan -> PS ----------------
    int   j  = key & 1023u;
    float sv = s2o[j];
    float Bv = __builtin_amdgcn_exp2f(sv * L2E);
    float Dv = __builtin_amdgcn_exp2f(sv * (ALPHAc * L2E));
    const float4* wr = (const float4*)(Whf + ((size_t)bh * Nn + j) * Dc);
    float4 w0 = wr[0], w1 = wr[1], w2 = wr[2], w3 = wr[3];
    float wh[16] = {w0.x,w0.y,w0.z,w0.w, w1.x,w1.y,w1.z,w1.w,
                    w2.x,w2.y,w2.z,w2.w, w3.x,w3.y,w3.z,w3.w};

    float v[34];
#pragma unroll
    for (int d = 0; d < 16; ++d) {
        v[d]      = Bv * wh[d];
        v[16 + d] = Dv * wh[d];
    }
    v[32] = Bv; v[33] = Dv;

#pragma unroll
    for (int c = 0; c < 34; ++c) {
        float x = v[c];
#pragma unroll
        for (int off = 1; off < 64; off <<= 1) {
            float o = __shfl_up(x, off, 64);
            if (lane >= off) x += o;
        }
        if (lane == 63) wtot[wv][c] = x;       // inclusive wave total
        float e = __shfl_up(x, 1, 64);
        v[c] = (lane == 0) ? 0.f : e;          // exclusive within wave
    }
    __syncthreads();

    if (t < 34) {
        float run = 0.f;
#pragma unroll
        for (int w = 0; w < 16; ++w) {
            float tmp = wtot[w][t];
            wtot[w][t] = run;                  // exclusive wave offset
            run += tmp;
        }
        PS[(size_t)1024 * 35 + t] = run;       // grand totals
    }
    __syncthreads();

    float* myrow = PS + (size_t)t * 35;        // stride 35 -> conflict-light
#pragma unroll
    for (int c = 0; c < 34; ++c)
        myrow[c] = v[c] + wtot[wv][c];
    __syncthreads();

    // ---------------- P3: combine ----------------
    int i = t;
    float R  = __builtin_amdgcn_exp2f(-0.8f * L2E * s1v);
    float* op = out + ((size_t)b * Nn + i) * (Hc * Dc) + hh * Dc;

    if (rowful[i]) {
        unsigned qk = (enc_f32(-s1v) & ~1023u) | 1023u;
        int p = 0;
#pragma unroll
        for (int step = 512; step >= 1; step >>= 1)
            if (skeys[p + step - 1] <= qk) p += step;   // p = #{keys <= qk}

        const float* Pp = PS + (size_t)p * 35;
        const float* Tp = PS + (size_t)1024 * 35;
        float den = (Tp[32] - Pp[32]) + R * Pp[33];
        float inv = 1.0f / den;
#pragma unroll
        for (int u = 0; u < 4; ++u) {
            float o0 = ((Tp[4*u+0] - Pp[4*u+0]) + R * Pp[16 + 4*u+0]) * inv;
            float o1 = ((Tp[4*u+1] - Pp[4*u+1]) + R * Pp[16 + 4*u+1]) * inv;
            float o2 = ((Tp[4*u+2] - Pp[4*u+2]) + R * Pp[16 + 4*u+2]) * inv;
            float o3 = ((Tp[4*u+3] - Pp[4*u+3]) + R * Pp[16 + 4*u+3]) * inv;
            ((float4*)op)[u] = make_float4(o0, o1, o2, o3);
        }
    } else {
        // exact fallback for masked rows (dead when adj is all-positive)
        float num[16];
#pragma unroll
        for (int d = 0; d < 16; ++d) num[d] = 0.f;
        float den = 0.f;
        for (int q = 0; q < Nn; ++q) {
            float aq = adj[(size_t)i * Nn + q];
            if (aq > 0.f) {
                float sq = s2o[q];
                float Bq = __builtin_amdgcn_exp2f(sq * L2E);
                float Dq = __builtin_amdgcn_exp2f(sq * (ALPHAc * L2E));
                float w_ = fmaxf(Bq, R * Dq);
                den += w_;
                const float* wq = Whf + ((size_t)bh * Nn + q) * Dc;
#pragma unroll
                for (int d = 0; d < 16; ++d)
                    num[d] = fmaf(w_, wq[d], num[d]);
            }
        }
        float inv = 1.0f / den;
#pragma unroll
        for (int d = 0; d < 16; ++d) op[d] = num[d] * inv;
    }
}

// ---------------------------------------------------------------------------
extern "C" void kernel_launch(void* const* d_in, const int* in_sizes, int n_in,
                              void* d_out, int out_size, void* d_ws, size_t ws_size,
                              hipStream_t stream)
{
    const float* hbuf = (const float*)d_in[0];   // (B,N,F)
    const float* adj  = (const float*)d_in[1];   // (N,N)
    const float* W    = (const float*)d_in[2];   // (H,F,D)
    const float* a    = (const float*)d_in[3];   // (H,2D,1)
    float* out = (float*)d_out;                  // (B,N,H*D) fp32

    // ws: Whf f32 (96*1024*16 = 6.3 MB) | rowful (1024 ints)
    float* Whf  = (float*)d_ws;
    int* rowful = (int*)(Whf + (size_t)Bc * Hc * Nn * Dc);

    gat_rowful<<<dim3(Nn), dim3(256), 0, stream>>>(adj, rowful);
    gat_fused<<<dim3(Bc * Hc), dim3(1024), 0, stream>>>(
        hbuf, W, a, adj, rowful, Whf, out);
}

// Round 7
// 35.148 us; speedup vs baseline: 2.1574x; 1.2599x over previous
//
#include <hip/hip_runtime.h>
#include <math.h>

// GAT: B=32, N=1024, F=64, H=3, D=16
constexpr int Bc = 32, Nn = 1024, Fc = 64, Hc = 3, Dc = 16;
constexpr float ALPHAc = 0.2f;
constexpr float L2E    = 1.44269504088896340736f;

__device__ __forceinline__ unsigned enc_f32(float x) {
    unsigned b = __builtin_bit_cast(unsigned, x);
    return (b & 0x80000000u) ? ~b : (b | 0x80000000u);
}

// DPP-based inclusive wave(64) scan: row_shr 1/2/4/8 then row_bcast 15/31.
// Pure VALU — no LDS pipe. old=0 so masked-out rows add 0.
template <int CTRL, int RMASK, bool BC>
__device__ __forceinline__ float dpp_acc(float x) {
    int s = __builtin_amdgcn_update_dpp(0, __builtin_bit_cast(int, x),
                                        CTRL, RMASK, 0xF, BC);
    return x + __builtin_bit_cast(float, s);
}
__device__ __forceinline__ float wave_incl_scan(float x) {
    x = dpp_acc<0x111, 0xF, true >(x);   // row_shr:1
    x = dpp_acc<0x112, 0xF, true >(x);   // row_shr:2
    x = dpp_acc<0x114, 0xF, true >(x);   // row_shr:4
    x = dpp_acc<0x118, 0xF, true >(x);   // row_shr:8
    x = dpp_acc<0x142, 0xa, false>(x);   // row_bcast:15 -> rows 1,3
    x = dpp_acc<0x143, 0xc, false>(x);   // row_bcast:31 -> rows 2,3
    return x;
}

// ---------------------------------------------------------------------------
// K0: rowful[i] = all(adj[i][:] > 0).  One block per row.
// ---------------------------------------------------------------------------
__global__ __launch_bounds__(256) void gat_rowful(
    const float* __restrict__ adj, int* __restrict__ rowful)
{
    __shared__ int rf;
    int row = blockIdx.x, t = threadIdx.x;
    if (t == 0) rf = 1;
    __syncthreads();
    float4 v = ((const float4*)(adj + (size_t)row * Nn))[t];
    bool ok = (v.x > 0.f) && (v.y > 0.f) && (v.z > 0.f) && (v.w > 0.f);
    if (!__all((int)ok)) {
        if ((t & 63) == 0) atomicAnd(&rf, 0);
    }
    __syncthreads();
    if (t == 0) rowful[row] = rf;
}

// ---------------------------------------------------------------------------
// K1: one block per (b,h), 1024 threads.
//  P0: thread t=n: Wh row, s1, s2; Whf->global(L2); s2o->LDS.
//  P1: hybrid bitonic sort (u32 = 22b trunc s2 | 10b idx): wave-local via
//      shfl, cross-wave stages double-buffered in LDS (1 barrier/stage).
//  P2: v[34]=(B*Wh, D*Wh, B, D); DPP wave scan + wave-offset scan ->
//      PS[1025][35] in LDS (row 1024 = totals).
//  P3: row i: binary search on sorted keys, O(1) combine.
// ---------------------------------------------------------------------------
__global__ __launch_bounds__(1024, 1) void gat_fused(
    const float* __restrict__ hbuf, const float* __restrict__ W,
    const float* __restrict__ a, const float* __restrict__ adj,
    const int* __restrict__ rowful, float* Whf, float* __restrict__ out)
{
    // 143,500 + 4,096*2 + 4,096 + 2,176 = 157,964 B LDS
    __shared__ __align__(16) float    PS[1025 * 35];
    __shared__ __align__(16) unsigned skA[Nn], skB[Nn];
    __shared__ __align__(16) float    s2o[Nn];
    __shared__ float wtot[16][34];

    int bh = blockIdx.x;
    int hh = bh % Hc, b = bh / Hc;
    int t  = threadIdx.x;            // n in P0; sorted slot in P2; row i in P3
    int wv = t >> 6, lane = t & 63;

    // ---------------- P0: Wh, s1, s2 ----------------
    const float4* h4 = (const float4*)(hbuf + ((size_t)b * Nn + t) * Fc);
    const float*  Wp = W + (size_t)hh * Fc * Dc;

    float acc[Dc];
#pragma unroll
    for (int d = 0; d < Dc; ++d) acc[d] = 0.f;

#pragma unroll
    for (int q = 0; q < Fc / 4; ++q) {
        float4 hv = h4[q];
#pragma unroll
        for (int c = 0; c < 4; ++c) {
            float hv1 = (c == 0) ? hv.x : (c == 1) ? hv.y : (c == 2) ? hv.z : hv.w;
            const float4* wrp = (const float4*)(Wp + (4 * q + c) * Dc);
#pragma unroll
            for (int u = 0; u < 4; ++u) {
                float4 wq = wrp[u];
                acc[4*u+0] = fmaf(hv1, wq.x, acc[4*u+0]);
                acc[4*u+1] = fmaf(hv1, wq.y, acc[4*u+1]);
                acc[4*u+2] = fmaf(hv1, wq.z, acc[4*u+2]);
                acc[4*u+3] = fmaf(hv1, wq.w, acc[4*u+3]);
            }
        }
    }

    float4* wf = (float4*)(Whf + ((size_t)bh * Nn + t) * Dc);
#pragma unroll
    for (int u = 0; u < 4; ++u)
        wf[u] = make_float4(acc[4*u+0], acc[4*u+1], acc[4*u+2], acc[4*u+3]);

    const float* ap = a + (size_t)hh * 2 * Dc;
    float s1v = 0.f, s2v = 0.f;
#pragma unroll
    for (int d = 0; d < Dc; ++d) {
        s1v = fmaf(acc[d], ap[d],      s1v);
        s2v = fmaf(acc[d], ap[Dc + d], s2v);
    }
    s2o[t] = s2v;

    // ---------------- P1: hybrid bitonic sort (u32 keys) ----------------
    unsigned key = (enc_f32(s2v) & ~1023u) | (unsigned)t;

    // wave-local stages (k=2..64) — registers only
#pragma unroll
    for (int k = 2; k <= 64; k <<= 1) {
#pragma unroll
        for (int s = k >> 1; s >= 1; s >>= 1) {
            unsigned other = (unsigned)__shfl_xor((int)key, s, 64);
            bool dirUp = ((t & k) == 0);
            bool lower = ((lane & s) == 0);
            unsigned mn = key < other ? key : other;
            unsigned mx = key < other ? other : key;
            key = (lower == dirUp) ? mn : mx;
        }
    }
    // cross-wave merges (k=128..1024): s>=64 double-buffered LDS (1 barrier
    // each: stage n writes buf P, bar, reads P; stage n+1 uses buf Q; the
    // next write to P (stage n+2) is behind stage n+1's barrier).
    unsigned* bufs[2] = {skA, skB};
    int pb = 0;
#pragma unroll
    for (int k = 128; k <= 1024; k <<= 1) {
#pragma unroll
        for (int s = k >> 1; s >= 64; s >>= 1) {
            bufs[pb][t] = key;
            __syncthreads();
            unsigned other = bufs[pb][t ^ s];
            bool dirUp = ((t & k) == 0);
            bool lower = ((t & s) == 0);
            unsigned mn = key < other ? key : other;
            unsigned mx = key < other ? other : key;
            key = (lower == dirUp) ? mn : mx;
            pb ^= 1;
        }
#pragma unroll
        for (int s = 32; s >= 1; s >>= 1) {
            unsigned other = (unsigned)__shfl_xor((int)key, s, 64);
            bool dirUp = ((t & k) == 0);
            bool lower = ((lane & s) == 0);
            unsigned mn = key < other ? key : other;
            unsigned mx = key < other ? other : key;
            key = (lower == dirUp) ? mn : mx;
        }
    }
    unsigned* sorted = bufs[pb];
    sorted[t] = key;     // visible to P3 after P2's barriers (prev reads of
                         // this buffer are behind the last sort barrier)

    // ---------------- P2: v + block exclusive scan -> PS ----------------
    int   j  = key & 1023u;
    float sv = s2o[j];
    float Bv = __builtin_amdgcn_exp2f(sv * L2E);
    float Dv = __builtin_amdgcn_exp2f(sv * (ALPHAc * L2E));
    const float4* wr = (const float4*)(Whf + ((size_t)bh * Nn + j) * Dc);
    float4 w0 = wr[0], w1 = wr[1], w2 = wr[2], w3 = wr[3];
    float wh[16] = {w0.x,w0.y,w0.z,w0.w, w1.x,w1.y,w1.z,w1.w,
                    w2.x,w2.y,w2.z,w2.w, w3.x,w3.y,w3.z,w3.w};

    float v[34];
#pragma unroll
    for (int d = 0; d < 16; ++d) {
        v[d]      = Bv * wh[d];
        v[16 + d] = Dv * wh[d];
    }
    v[32] = Bv; v[33] = Dv;

    // DPP inclusive scan per channel (pure VALU), then exclusive via subtract
#pragma unroll
    for (int c = 0; c < 34; ++c) {
        float inc = wave_incl_scan(v[c]);
        if (lane == 63) wtot[wv][c] = inc;     // inclusive wave total
        v[c] = inc - v[c];                     // exclusive within wave
    }
    __syncthreads();

    if (t < 34) {
        float run = 0.f;
#pragma unroll
        for (int w = 0; w < 16; ++w) {
            float tmp = wtot[w][t];
            wtot[w][t] = run;                  // exclusive wave offset
            run += tmp;
        }
        PS[(size_t)1024 * 35 + t] = run;       // grand totals
    }
    __syncthreads();

    float* myrow = PS + (size_t)t * 35;        // stride 35 -> conflict-light
#pragma unroll
    for (int c = 0; c < 34; ++c)
        myrow[c] = v[c] + wtot[wv][c];
    __syncthreads();

    // ---------------- P3: combine ----------------
    int i = t;
    float R  = __builtin_amdgcn_exp2f(-0.8f * L2E * s1v);
    float* op = out + ((size_t)b * Nn + i) * (Hc * Dc) + hh * Dc;

    if (rowful[i]) {
        unsigned qk = (enc_f32(-s1v) & ~1023u) | 1023u;
        int p = 0;
#pragma unroll
        for (int step = 512; step >= 1; step >>= 1)
            if (sorted[p + step - 1] <= qk) p += step;   // p = #{keys <= qk}

        const float* Pp = PS + (size_t)p * 35;
        const float* Tp = PS + (size_t)1024 * 35;
        float den = (Tp[32] - Pp[32]) + R * Pp[33];
        float inv = 1.0f / den;
#pragma unroll
        for (int u = 0; u < 4; ++u) {
            float o0 = ((Tp[4*u+0] - Pp[4*u+0]) + R * Pp[16 + 4*u+0]) * inv;
            float o1 = ((Tp[4*u+1] - Pp[4*u+1]) + R * Pp[16 + 4*u+1]) * inv;
            float o2 = ((Tp[4*u+2] - Pp[4*u+2]) + R * Pp[16 + 4*u+2]) * inv;
            float o3 = ((Tp[4*u+3] - Pp[4*u+3]) + R * Pp[16 + 4*u+3]) * inv;
            ((float4*)op)[u] = make_float4(o0, o1, o2, o3);
        }
    } else {
        // exact fallback for masked rows (dead when adj is all-positive)
        float num[16];
#pragma unroll
        for (int d = 0; d < 16; ++d) num[d] = 0.f;
        float den = 0.f;
        for (int q = 0; q < Nn; ++q) {
            float aq = adj[(size_t)i * Nn + q];
            if (aq > 0.f) {
                float sq = s2o[q];
                float Bq = __builtin_amdgcn_exp2f(sq * L2E);
                float Dq = __builtin_amdgcn_exp2f(sq * (ALPHAc * L2E));
                float w_ = fmaxf(Bq, R * Dq);
                den += w_;
                const float* wq = Whf + ((size_t)bh * Nn + q) * Dc;
#pragma unroll
                for (int d = 0; d < 16; ++d)
                    num[d] = fmaf(w_, wq[d], num[d]);
            }
        }
        float inv = 1.0f / den;
#pragma unroll
        for (int d = 0; d < 16; ++d) op[d] = num[d] * inv;
    }
}

// ---------------------------------------------------------------------------
extern "C" void kernel_launch(void* const* d_in, const int* in_sizes, int n_in,
                              void* d_out, int out_size, void* d_ws, size_t ws_size,
                              hipStream_t stream)
{
    const float* hbuf = (const float*)d_in[0];   // (B,N,F)
    const float* adj  = (const float*)d_in[1];   // (N,N)
    const float* W    = (const float*)d_in[2];   // (H,F,D)
    const float* a    = (const float*)d_in[3];   // (H,2D,1)
    float* out = (float*)d_out;                  // (B,N,H*D) fp32

    // ws: Whf f32 (96*1024*16 = 6.3 MB) | rowful (1024 ints)
    float* Whf  = (float*)d_ws;
    int* rowful = (int*)(Whf + (size_t)Bc * Hc * Nn * Dc);

    gat_rowful<<<dim3(Nn), dim3(256), 0, stream>>>(adj, rowful);
    gat_fused<<<dim3(Bc * Hc), dim3(1024), 0, stream>>>(
        hbuf, W, a, adj, rowful, Whf, out);
}